// Round 17
// baseline (247.091 us; speedup 1.0000x reference)
//
#include <hip/hip_runtime.h>

#define NP 100000
#define NA 50000
#define NE 500000
#define HID 128
#define NTOT (2*NP + NA)   // 250000 concatenated dst nodes
#define NE3 (3*NE)         // 1,500,000
#define CHUNK 4096
#define NCHK 367           // ceil(NE3/CHUNK)
#define BSH 9              // bin = dst >> 9 (512 dsts/bin)
#define NBIN 489           // ceil(250000/512)
#define MAXBIN 6144        // max edges/bin staged in LDS

typedef __attribute__((ext_vector_type(8))) short short8;
typedef __attribute__((ext_vector_type(4))) float floatx4;

// ---------------- workspace layout (bytes) ----------------
// xbf_p u16[NP*128] @ 0 (25.6MB) ; cnt int[250k] @ 25,600,000
// part u64[1.5M] @ 33,600,000 (12MB)
// pcnt u32[367*512] @ 45,600,000 ; binStart u32[513] @ 46,351,616
// WcatP(frag-major) @ 46,360,000 (98,304) ; WcatA @ 46,458,304 (65,536) ; wsB @ 46,523,840
#define OFF_CNT  25600000ull
#define OFF_PART 33600000ull
#define OFF_PCNT 45600000ull
#define OFF_BST  46351616ull
#define OFF_WP   46360000ull
#define OFF_WA   46458304ull
#define OFF_B    46523840ull

__device__ __forceinline__ unsigned short f2bf(float f) {
    unsigned int u = __builtin_bit_cast(unsigned int, f);
    u += 0x7FFFu + ((u >> 16) & 1u);   // RNE
    return (unsigned short)(u >> 16);
}
__device__ __forceinline__ unsigned int pack2(float a, float b) {
    return (unsigned int)f2bf(a) | ((unsigned int)f2bf(b) << 16);
}
__device__ __forceinline__ float bflo(unsigned int u) {
    return __builtin_bit_cast(float, u << 16);
}
__device__ __forceinline__ float bfhi(unsigned int u) {
    return __builtin_bit_cast(float, u & 0xFFFF0000u);
}

// edge e in [0,NE3): concatenated dst / src
__device__ __forceinline__ int edst(int e, const int* eic, const int* eiw, const int* eiwr) {
    if (e < NE)   return eic[NE + e];
    if (e < 2*NE) return NP + eiw[e];
    return 2*NP + eiwr[e - NE];
}
__device__ __forceinline__ int esrc(int e, const int* eic, const int* eiw, const int* eiwr) {
    if (e < NE)   return eic[e];
    if (e < 2*NE) return eiw[e - NE];
    return eiwr[e - 2*NE];
}

// ---------------- fp32 -> bf16 for BOTH node sets in one launch ----------------
__global__ __launch_bounds__(256) void to_bf16_both(const float* __restrict__ xp,
                                                    const float* __restrict__ xa,
                                                    unsigned int* __restrict__ xbf_p,
                                                    unsigned int* __restrict__ outa_u) {
    int i = blockIdx.x * blockDim.x + threadIdx.x;
    const float* src; unsigned int* dst; int stride; int i2;
    if (i < NP*16) { src = xp; dst = xbf_p; stride = 64; i2 = i; }
    else if (i < (NP+NA)*16) { src = xa; dst = outa_u; stride = 128; i2 = i - NP*16; }
    else return;
    int row = i2 >> 4, j = i2 & 15;
    floatx4 u0 = ((const floatx4*)src)[(long long)i2*2];
    floatx4 u1 = ((const floatx4*)src)[(long long)i2*2 + 1];
    uint4 o;
    o.x = pack2(u0[0], u0[1]); o.y = pack2(u0[2], u0[3]);
    o.z = pack2(u1[0], u1[1]); o.w = pack2(u1[2], u1[3]);
    *(uint4*)(dst + (long long)row * stride + j*4) = o;
}

// ---------------- weight fusion -> FRAGMENT-MAJOR layout ----------------
__global__ void fuse_w(const float* __restrict__ Wc_p, const float* __restrict__ Ws_p,
                       const float* __restrict__ W_cites, const float* __restrict__ W_writes,
                       const float* __restrict__ Wc_a, const float* __restrict__ Ws_a,
                       const float* __restrict__ W_written,
                       unsigned short* __restrict__ WcatP, unsigned short* __restrict__ WcatA) {
    int m = blockIdx.x >> 7;
    int r = blockIdx.x & 127;   // output col of GEMM
    int c = threadIdx.x;        // k within 128-segment
    const float* L; const float* R; float scale = 1.f;
    switch (m) {
        case 0:  L = Wc_p + r*256;       R = Ws_p;      break;
        case 1:  L = Wc_p + r*256 + 128; R = W_cites;   scale = 0.5f; break;
        case 2:  L = Wc_p + r*256 + 128; R = W_writes;  scale = 0.5f; break;
        case 3:  L = Wc_a + r*256;       R = Ws_a;      break;
        default: L = Wc_a + r*256 + 128; R = W_written; break;
    }
    float acc = 0.f;
    for (int k = 0; k < 128; ++k) acc += L[k] * R[k*128 + c];
    unsigned short v = f2bf(scale * acc);
    int kcat = (m < 3 ? m : m - 3) * 128 + c;
    int s  = kcat >> 5;
    int kg = (kcat >> 3) & 3;
    int j  = kcat & 7;
    int cg = r >> 4;
    int l15 = r & 15;
    long long idx = ((((long long)s*8 + cg)*64) + kg*16 + l15)*8 + j;
    if (m < 3) WcatP[idx] = v;
    else       WcatA[idx] = v;
}

__global__ void fuse_b(const float* __restrict__ Wc_p, const float* __restrict__ bs_p,
                       const float* __restrict__ bc_p, const float* __restrict__ b_cites,
                       const float* __restrict__ b_writes,
                       const float* __restrict__ Wc_a, const float* __restrict__ bs_a,
                       const float* __restrict__ bc_a, const float* __restrict__ b_written,
                       float* __restrict__ wsB) {
    int t = blockIdx.x * blockDim.x + threadIdx.x;
    if (t >= 640) return;
    int m = t >> 7, j = t & 127;
    float acc = 0.f;
    switch (m) {
        case 0:  for (int k = 0; k < 128; ++k) acc += Wc_p[j*256+k]     * bs_p[k];     acc += bc_p[j]; break;
        case 1:  for (int k = 0; k < 128; ++k) acc += Wc_p[j*256+128+k] * b_cites[k];  acc *= 0.5f;    break;
        case 2:  for (int k = 0; k < 128; ++k) acc += Wc_p[j*256+128+k] * b_writes[k]; acc *= 0.5f;    break;
        case 3:  for (int k = 0; k < 128; ++k) acc += Wc_a[j*256+k]     * bs_a[k];     acc += bc_a[j]; break;
        default: for (int k = 0; k < 128; ++k) acc += Wc_a[j*256+128+k] * b_written[k];                break;
    }
    wsB[m*128 + j] = acc;
}

// ---------------- P1: per-(chunk,bin) counts via LDS histogram ----------------
__global__ __launch_bounds__(1024) void part_count(const int* __restrict__ eic,
                                                   const int* __restrict__ eiw,
                                                   const int* __restrict__ eiwr,
                                                   unsigned int* __restrict__ pcnt) {
    __shared__ int lc[512];
    int t = threadIdx.x;
    if (t < 512) lc[t] = 0;
    __syncthreads();
    int base = blockIdx.x * CHUNK;
#pragma unroll
    for (int k = 0; k < 4; ++k) {
        int e = base + k*1024 + t;
        if (e < NE3) atomicAdd(&lc[edst(e, eic, eiw, eiwr) >> BSH], 1);
    }
    __syncthreads();
    if (t < 512) pcnt[blockIdx.x*512 + t] = (unsigned int)lc[t];
}

// ---------------- P2a: bin totals + exclusive scan -> binStart ----------------
__global__ __launch_bounds__(512) void bin_scan(const unsigned int* __restrict__ pcnt,
                                                unsigned int* __restrict__ binStart) {
    __shared__ unsigned int s[512];
    int t = threadIdx.x;
    unsigned int tot = 0;
    for (int c = 0; c < NCHK; ++c) tot += pcnt[c*512 + t];
    s[t] = tot; __syncthreads();
    for (int off = 1; off < 512; off <<= 1) {
        unsigned int u = (t >= off) ? s[t-off] : 0;
        __syncthreads();
        s[t] += u;
        __syncthreads();
    }
    binStart[t] = s[t] - tot;
    if (t == 511) binStart[512] = s[t];   // == NE3
}

// ---------------- P2b: per-bin scan over chunks (in-place pcnt -> offsets) ----
__global__ __launch_bounds__(512) void chunk_scan(unsigned int* __restrict__ pcnt,
                                                  const unsigned int* __restrict__ binStart) {
    __shared__ unsigned int s[512];
    int bin = blockIdx.x;
    int t = threadIdx.x;
    unsigned int v = (t < NCHK) ? pcnt[t*512 + bin] : 0;
    s[t] = v; __syncthreads();
    for (int off = 1; off < 512; off <<= 1) {
        unsigned int u = (t >= off) ? s[t-off] : 0;
        __syncthreads();
        s[t] += u;
        __syncthreads();
    }
    if (t < NCHK) pcnt[t*512 + bin] = binStart[bin] + s[t] - v;
}

// ---------------- P3: partition-scatter, LDS-staged by bin ----------------
__global__ __launch_bounds__(1024) void part_scatter(const int* __restrict__ eic,
                                                     const int* __restrict__ eiw,
                                                     const int* __restrict__ eiwr,
                                                     const unsigned int* __restrict__ pcnt,
                                                     unsigned long long* __restrict__ part) {
    __shared__ unsigned int lcnt[512], lexc[512], lrank[512], ssc[512];
    __shared__ unsigned long long stage[CHUNK];
    int t = threadIdx.x;
    if (t < 512) { lcnt[t] = 0; lrank[t] = 0; }
    __syncthreads();
    int base = blockIdx.x * CHUNK;
    int dd[4], ss4[4];
#pragma unroll
    for (int k = 0; k < 4; ++k) {
        int e = base + k*1024 + t;
        dd[k] = -1;
        if (e < NE3) {
            dd[k] = edst(e, eic, eiw, eiwr);
            ss4[k] = esrc(e, eic, eiw, eiwr);
            atomicAdd(&lcnt[dd[k] >> BSH], 1);
        }
    }
    __syncthreads();
    unsigned int v0 = (t < 512) ? lcnt[t] : 0;
    if (t < 512) ssc[t] = v0;
    __syncthreads();
    for (int off = 1; off < 512; off <<= 1) {
        unsigned int u = 0;
        if (t < 512 && t >= off) u = ssc[t-off];
        __syncthreads();
        if (t < 512) ssc[t] += u;
        __syncthreads();
    }
    if (t < 512) lexc[t] = ssc[t] - v0;
    __syncthreads();
#pragma unroll
    for (int k = 0; k < 4; ++k) {
        if (dd[k] >= 0) {
            int b = dd[k] >> BSH;
            unsigned int r = atomicAdd(&lrank[b], 1);
            stage[lexc[b] + r] = ((unsigned long long)(unsigned int)dd[k] << 32)
                               | (unsigned int)ss4[k];
        }
    }
    __syncthreads();
    int nE = min(NE3 - base, CHUNK);
    for (int i = t; i < nE; i += 1024) {
        unsigned long long pr = stage[i];
        int b = (int)(pr >> 32) >> BSH;
        unsigned int pos = pcnt[blockIdx.x*512 + b] + ((unsigned int)i - lexc[b]);
        part[pos] = pr;
    }
}

// ---------------- P4+aggregate MERGED: bin-local CSR sort in LDS, then ---------
// gather-aggregate with LDS-resident indices (no srcIdx round-trip, no global
// index-load latency in the per-dst chain). One block per 512-dst bin; 16 waves;
// wave wv handles dsts wv, wv+16, ... (32 dsts). Indices: LDS broadcast read +
// readfirstlane -> saddr-form row gathers (zero per-lane addr VALU).
__global__ __launch_bounds__(1024) void bin_csr_agg(
        const unsigned long long* __restrict__ part,
        const unsigned int* __restrict__ binStart,
        const unsigned int* __restrict__ xbfp,   // bf16 paper rows, stride 64 u32
        unsigned int* __restrict__ outp_u,       // out_p as u32, row stride 128
        unsigned int* __restrict__ outa_u,       // out_a as u32, row stride 128
        int* __restrict__ cnt_g) {
    __shared__ int lcnt[512];
    __shared__ unsigned int lexc[512], ssc[512];
    __shared__ int lsrc[MAXBIN];
    int bin = blockIdx.x, t = threadIdx.x;
    unsigned int beg = binStart[bin];
    int nE = (int)(binStart[bin+1] - beg);
    if (nE > MAXBIN) nE = MAXBIN;
    int d0 = bin << BSH;
    if (t < 512) lcnt[t] = 0;
    __syncthreads();
    for (int i = t; i < nE; i += 1024)
        atomicAdd(&lcnt[(int)(part[beg+i] >> 32) - d0], 1);
    __syncthreads();
    unsigned int v0 = (t < 512) ? (unsigned int)lcnt[t] : 0;
    if (t < 512) ssc[t] = v0;
    __syncthreads();
    for (int off = 1; off < 512; off <<= 1) {
        unsigned int u = 0;
        if (t < 512 && t >= off) u = ssc[t-off];
        __syncthreads();
        if (t < 512) ssc[t] += u;
        __syncthreads();
    }
    if (t < 512) { lexc[t] = ssc[t] - v0; lcnt[t] = 0; }   // lcnt reused as rank
    __syncthreads();
    for (int i = t; i < nE; i += 1024) {
        unsigned long long pr = part[beg+i];
        int ld = (int)(pr >> 32) - d0;
        int r = atomicAdd(&lcnt[ld], 1);
        lsrc[lexc[ld] + r] = (int)(unsigned int)pr;
    }
    __syncthreads();
    // cnt out (GEMM bias gating)
    {
        int gd = d0 + t;
        if (t < 512 && gd < NTOT) cnt_g[gd] = lcnt[t];
    }
    // ---- gather-aggregate phase ----
    int wv = t >> 6, lane = t & 63;
    for (int ld = wv; ld < 512; ld += 16) {
        int gw = d0 + ld;
        if (gw >= NTOT) break;
        int n    = lcnt[ld];     // uniform LDS broadcast
        int begL = (int)lexc[ld];

        const unsigned int* src; int sshift; unsigned int* mean;
        if (gw < NP) {
            src = xbfp; sshift = 6;
            mean = outp_u + (long long)gw * 128 + lane;
        } else if (gw < 2*NP) {
            src = outa_u; sshift = 7;
            mean = outp_u + (long long)(gw - NP) * 128 + 64 + lane;
        } else {
            src = xbfp; sshift = 6;
            mean = outa_u + (long long)(gw - 2*NP) * 128 + 64 + lane;
        }

        float l0=0.f,h0=0.f,l1=0.f,h1=0.f,l2=0.f,h2=0.f,l3=0.f,h3=0.f;
        int nm1 = n - 1;
        for (int j = 0; j < n; j += 8) {
            int s0 = __builtin_amdgcn_readfirstlane(lsrc[begL + min(j + 0, nm1)]);
            int s1 = __builtin_amdgcn_readfirstlane(lsrc[begL + min(j + 1, nm1)]);
            int s2 = __builtin_amdgcn_readfirstlane(lsrc[begL + min(j + 2, nm1)]);
            int s3 = __builtin_amdgcn_readfirstlane(lsrc[begL + min(j + 3, nm1)]);
            int s4 = __builtin_amdgcn_readfirstlane(lsrc[begL + min(j + 4, nm1)]);
            int s5 = __builtin_amdgcn_readfirstlane(lsrc[begL + min(j + 5, nm1)]);
            int s6 = __builtin_amdgcn_readfirstlane(lsrc[begL + min(j + 6, nm1)]);
            int s7 = __builtin_amdgcn_readfirstlane(lsrc[begL + min(j + 7, nm1)]);
            unsigned int u0 = src[(s0 << sshift) + lane];
            unsigned int u1 = src[(s1 << sshift) + lane];
            unsigned int u2 = src[(s2 << sshift) + lane];
            unsigned int u3 = src[(s3 << sshift) + lane];
            unsigned int u4 = src[(s4 << sshift) + lane];
            unsigned int u5 = src[(s5 << sshift) + lane];
            unsigned int u6 = src[(s6 << sshift) + lane];
            unsigned int u7 = src[(s7 << sshift) + lane];
            float m1f = (j + 1 < n) ? 1.f : 0.f;
            float m2f = (j + 2 < n) ? 1.f : 0.f;
            float m3f = (j + 3 < n) ? 1.f : 0.f;
            float m4f = (j + 4 < n) ? 1.f : 0.f;
            float m5f = (j + 5 < n) ? 1.f : 0.f;
            float m6f = (j + 6 < n) ? 1.f : 0.f;
            float m7f = (j + 7 < n) ? 1.f : 0.f;
            l0 += bflo(u0);               h0 += bfhi(u0);
            l1 = fmaf(m1f, bflo(u1), l1); h1 = fmaf(m1f, bfhi(u1), h1);
            l2 = fmaf(m2f, bflo(u2), l2); h2 = fmaf(m2f, bfhi(u2), h2);
            l3 = fmaf(m3f, bflo(u3), l3); h3 = fmaf(m3f, bfhi(u3), h3);
            l0 = fmaf(m4f, bflo(u4), l0); h0 = fmaf(m4f, bfhi(u4), h0);
            l1 = fmaf(m5f, bflo(u5), l1); h1 = fmaf(m5f, bfhi(u5), h1);
            l2 = fmaf(m6f, bflo(u6), l2); h2 = fmaf(m6f, bfhi(u6), h2);
            l3 = fmaf(m7f, bflo(u7), l3); h3 = fmaf(m7f, bfhi(u7), h3);
        }
        float lsum = (l0 + l1) + (l2 + l3);
        float hsum = (h0 + h1) + (h2 + h3);
        float sc = 1.f / (float)max(n, 1);
        *mean = pack2(lsum * sc, hsum * sc);
    }
}

// ---------------- MFMA GEMM (frag-major coalesced B loads) ----------------
template<int NSEG, bool S0SAFE, int S0STRIDE>
__global__ __launch_bounds__(256) void mfma_gemm(
        const unsigned short* __restrict__ a0src,
        const unsigned short* __restrict__ m1,    // row stride 256 u16
        const unsigned short* __restrict__ m2,    // row stride 256 u16
        const int* __restrict__ cnt1,
        const int* __restrict__ cnt2,
        const unsigned short* __restrict__ WcatF, // fragment-major
        const float* __restrict__ b0,
        const float* __restrict__ b1,
        const float* __restrict__ b2,
        float* __restrict__ out, int nRows) {
    constexpr int SOFF = S0SAFE ? 4 : 0;
    constexpr int NPRE = NSEG * 4 - SOFF;
    int tid = threadIdx.x;
    int lane = tid & 63;
    int wid = tid >> 6;
    int wm = wid >> 1, wn = wid & 1;
    int row0 = blockIdx.x * 64 + wm * 32;
    int colBase = wn * 64;
    int l15 = lane & 15;
    int kg = lane >> 4;

    int rA0 = min(row0 + l15,      nRows - 1);
    int rA1 = min(row0 + 16 + l15, nRows - 1);

    short8 pa[NPRE][2];
#pragma unroll
    for (int i = 0; i < NPRE; ++i) {
        int s = i + SOFF;
        int kk = (s & 3) * 32 + kg * 8;
        const unsigned short* src = (!S0SAFE && s < 4) ? a0src : ((s >= 8) ? m2 : m1);
        pa[i][0] = *(const short8*)(src + (long long)rA0 * 256 + kk);
        pa[i][1] = *(const short8*)(src + (long long)rA1 * 256 + kk);
    }
    asm volatile("s_waitcnt vmcnt(0)" ::: "memory");  // preloads resident pre-barrier
    __syncthreads();   // all out-buffer reads done before any epilogue write

    floatx4 acc[2][4] = {};

#pragma unroll
    for (int s = 0; s < NSEG * 4; ++s) {
        int kk = (s & 3) * 32 + kg * 8;
        short8 a0, a1;
        if (S0SAFE && s < 4) {
            a0 = *(const short8*)(a0src + (long long)rA0 * S0STRIDE + kk);
            a1 = *(const short8*)(a0src + (long long)rA1 * S0STRIDE + kk);
        } else {
            a0 = pa[s - SOFF][0];
            a1 = pa[s - SOFF][1];
        }
        const unsigned short* wb = WcatF + ((long long)(s*8 + wn*4) * 64 + lane) * 8;
        short8 bf0 = *(const short8*)(wb);
        short8 bf1 = *(const short8*)(wb + 64*8);
        short8 bf2 = *(const short8*)(wb + 2*64*8);
        short8 bf3 = *(const short8*)(wb + 3*64*8);

        acc[0][0] = __builtin_amdgcn_mfma_f32_16x16x32_bf16(a0, bf0, acc[0][0], 0, 0, 0);
        acc[0][1] = __builtin_amdgcn_mfma_f32_16x16x32_bf16(a0, bf1, acc[0][1], 0, 0, 0);
        acc[0][2] = __builtin_amdgcn_mfma_f32_16x16x32_bf16(a0, bf2, acc[0][2], 0, 0, 0);
        acc[0][3] = __builtin_amdgcn_mfma_f32_16x16x32_bf16(a0, bf3, acc[0][3], 0, 0, 0);
        acc[1][0] = __builtin_amdgcn_mfma_f32_16x16x32_bf16(a1, bf0, acc[1][0], 0, 0, 0);
        acc[1][1] = __builtin_amdgcn_mfma_f32_16x16x32_bf16(a1, bf1, acc[1][1], 0, 0, 0);
        acc[1][2] = __builtin_amdgcn_mfma_f32_16x16x32_bf16(a1, bf2, acc[1][2], 0, 0, 0);
        acc[1][3] = __builtin_amdgcn_mfma_f32_16x16x32_bf16(a1, bf3, acc[1][3], 0, 0, 0);
    }

    float bb0[4], bb1[4], bb2[4];
#pragma unroll
    for (int n = 0; n < 4; ++n) {
        int col = colBase + n * 16 + l15;
        bb0[n] = b0[col];
        bb1[n] = b1[col];
        bb2[n] = (NSEG == 3) ? b2[col] : 0.f;
    }
    int rb = kg * 4;
#pragma unroll
    for (int m = 0; m < 2; ++m) {
#pragma unroll
        for (int r = 0; r < 4; ++r) {
            int gr = row0 + m * 16 + rb + r;
            if (gr >= nRows) continue;
            float mk1 = (cnt1[gr] > 0) ? 1.f : 0.f;
            float mk2 = (NSEG == 3) ? ((cnt2[gr] > 0) ? 1.f : 0.f) : 0.f;
            float* op = out + (long long)gr * 128 + colBase + l15;
#pragma unroll
            for (int n = 0; n < 4; ++n) {
                float v = acc[m][n][r] + bb0[n] + mk1 * bb1[n] + mk2 * bb2[n];
                op[n * 16] = fmaxf(v, 0.f);
            }
        }
    }
}

extern "C" void kernel_launch(void* const* d_in, const int* in_sizes, int n_in,
                              void* d_out, int out_size, void* d_ws, size_t ws_size,
                              hipStream_t stream) {
    const float* x_paper   = (const float*)d_in[0];
    const float* x_author  = (const float*)d_in[1];
    const int*   ei_cites  = (const int*)d_in[2];
    const int*   ei_writes = (const int*)d_in[3];
    const int*   ei_written= (const int*)d_in[4];
    const float* W_cites   = (const float*)d_in[5];
    const float* b_cites   = (const float*)d_in[6];
    const float* W_writes  = (const float*)d_in[7];
    const float* b_writes  = (const float*)d_in[8];
    const float* W_written = (const float*)d_in[9];
    const float* b_written = (const float*)d_in[10];
    const float* Ws_paper  = (const float*)d_in[11];
    const float* bs_paper  = (const float*)d_in[12];
    const float* Ws_author = (const float*)d_in[13];
    const float* bs_author = (const float*)d_in[14];
    const float* Wc_paper  = (const float*)d_in[15];
    const float* bc_paper  = (const float*)d_in[16];
    const float* Wc_author = (const float*)d_in[17];
    const float* bc_author = (const float*)d_in[18];

    char* ws = (char*)d_ws;
    unsigned int* xbf_p = (unsigned int*)ws;
    int* cnt      = (int*)(ws + OFF_CNT);
    unsigned long long* part = (unsigned long long*)(ws + OFF_PART);
    unsigned int* pcnt     = (unsigned int*)(ws + OFF_PCNT);
    unsigned int* binStart = (unsigned int*)(ws + OFF_BST);
    unsigned short* WcatP = (unsigned short*)(ws + OFF_WP);
    unsigned short* WcatA = (unsigned short*)(ws + OFF_WA);
    float* wsB = (float*)(ws + OFF_B);
    const float* bp0 = wsB;
    const float* bpc = wsB + 128;
    const float* bpw = wsB + 2*128;
    const float* ba0 = wsB + 3*128;
    const float* bab = wsB + 4*128;

    float* out_p = (float*)d_out;
    float* out_a = out_p + (long long)NP*HID;
    unsigned int* outp_u = (unsigned int*)out_p;
    unsigned int* outa_u = (unsigned int*)out_a;

    // bf16 stashes: x_paper -> ws; x_author -> out_a low halves
    to_bf16_both<<<((NP+NA)*16 + 255) / 256, 256, 0, stream>>>(
        x_paper, x_author, xbf_p, outa_u);
    fuse_w<<<640, 128, 0, stream>>>(Wc_paper, Ws_paper, W_cites, W_writes,
                                    Wc_author, Ws_author, W_written, WcatP, WcatA);
    fuse_b<<<3, 256, 0, stream>>>(Wc_paper, bs_paper, bc_paper, b_cites, b_writes,
                                  Wc_author, bs_author, bc_author, b_written, wsB);

    // partition: counts -> scans -> bin-grouped (dst,src) pairs
    part_count  <<<NCHK, 1024, 0, stream>>>(ei_cites, ei_writes, ei_written, pcnt);
    bin_scan    <<<1,    512,  0, stream>>>(pcnt, binStart);
    chunk_scan  <<<NBIN, 512,  0, stream>>>(pcnt, binStart);
    part_scatter<<<NCHK, 1024, 0, stream>>>(ei_cites, ei_writes, ei_written, pcnt, part);

    // merged bin-sort + gather-aggregate (indices stay in LDS)
    bin_csr_agg<<<NBIN, 1024, 0, stream>>>(part, binStart, xbf_p, outp_u, outa_u, cnt);

    // paper GEMM: seg0 = xbf_p (ws); m1/m2 = out_p interleaved
    mfma_gemm<3, true, 128><<<(NP + 63) / 64, 256, 0, stream>>>(
        (const unsigned short*)xbf_p,
        (const unsigned short*)outp_u, (const unsigned short*)outp_u + 128,
        cnt, cnt + NP, WcatP, bp0, bpc, bpw, out_p, NP);

    // author GEMM: seg0 = xbf_a (out_a low), m1 = ma (out_a high)
    mfma_gemm<2, false, 256><<<(NA + 63) / 64, 256, 0, stream>>>(
        (const unsigned short*)outa_u,
        (const unsigned short*)outa_u + 128, nullptr,
        cnt + 2*NP, nullptr, WcatA, ba0, bab, nullptr, out_a, NA);
}

// Round 18
// 221.780 us; speedup vs baseline: 1.1141x; 1.1141x over previous
//
#include <hip/hip_runtime.h>

#define NP 100000
#define NA 50000
#define NE 500000
#define HID 128
#define NTOT (2*NP + NA)   // 250000 concatenated dst nodes
#define NE3 (3*NE)         // 1,500,000
#define CHUNK 4096
#define NCHK 367           // ceil(NE3/CHUNK)
#define BSH 9              // bin = dst >> 9 (512 dsts/bin)
#define NBIN 489           // ceil(250000/512)
#define MAXBIN 6144        // max edges/bin staged in LDS

typedef __attribute__((ext_vector_type(8))) short short8;
typedef __attribute__((ext_vector_type(4))) float floatx4;

// ---------------- workspace layout (bytes) ----------------
// xbf_p u16[NP*128] @ 0 (25.6MB) ; cnt int[250k] @ 25,600,000 ; rowStart @ 26,600,000
// srcIdx int[1.5M] @ 27,600,000 (6MB) ; part u64[1.5M] @ 33,600,000 (12MB)
// pcnt u32[367*512] @ 45,600,000 ; binStart u32[513] @ 46,351,616
// WcatP(frag-major) @ 46,360,000 (98,304) ; WcatA @ 46,458,304 (65,536) ; wsB @ 46,523,840
#define OFF_CNT  25600000ull
#define OFF_ROW  26600000ull
#define OFF_SRC  27600000ull
#define OFF_PART 33600000ull
#define OFF_PCNT 45600000ull
#define OFF_BST  46351616ull
#define OFF_WP   46360000ull
#define OFF_WA   46458304ull
#define OFF_B    46523840ull

__device__ __forceinline__ unsigned short f2bf(float f) {
    unsigned int u = __builtin_bit_cast(unsigned int, f);
    u += 0x7FFFu + ((u >> 16) & 1u);   // RNE
    return (unsigned short)(u >> 16);
}
__device__ __forceinline__ unsigned int pack2(float a, float b) {
    return (unsigned int)f2bf(a) | ((unsigned int)f2bf(b) << 16);
}
__device__ __forceinline__ float bflo(unsigned int u) {
    return __builtin_bit_cast(float, u << 16);
}
__device__ __forceinline__ float bfhi(unsigned int u) {
    return __builtin_bit_cast(float, u & 0xFFFF0000u);
}

// edge e in [0,NE3): concatenated dst / src
__device__ __forceinline__ int edst(int e, const int* eic, const int* eiw, const int* eiwr) {
    if (e < NE)   return eic[NE + e];
    if (e < 2*NE) return NP + eiw[e];
    return 2*NP + eiwr[e - NE];
}
__device__ __forceinline__ int esrc(int e, const int* eic, const int* eiw, const int* eiwr) {
    if (e < NE)   return eic[e];
    if (e < 2*NE) return eiw[e - NE];
    return eiwr[e - 2*NE];
}

// ---------------- fp32 -> bf16 for BOTH node sets in one launch ----------------
__global__ __launch_bounds__(256) void to_bf16_both(const float* __restrict__ xp,
                                                    const float* __restrict__ xa,
                                                    unsigned int* __restrict__ xbf_p,
                                                    unsigned int* __restrict__ outa_u) {
    int i = blockIdx.x * blockDim.x + threadIdx.x;
    const float* src; unsigned int* dst; int stride; int i2;
    if (i < NP*16) { src = xp; dst = xbf_p; stride = 64; i2 = i; }
    else if (i < (NP+NA)*16) { src = xa; dst = outa_u; stride = 128; i2 = i - NP*16; }
    else return;
    int row = i2 >> 4, j = i2 & 15;
    floatx4 u0 = ((const floatx4*)src)[(long long)i2*2];
    floatx4 u1 = ((const floatx4*)src)[(long long)i2*2 + 1];
    uint4 o;
    o.x = pack2(u0[0], u0[1]); o.y = pack2(u0[2], u0[3]);
    o.z = pack2(u1[0], u1[1]); o.w = pack2(u1[2], u1[3]);
    *(uint4*)(dst + (long long)row * stride + j*4) = o;
}

// ---------------- weight fusion -> FRAGMENT-MAJOR layout ----------------
__global__ void fuse_w(const float* __restrict__ Wc_p, const float* __restrict__ Ws_p,
                       const float* __restrict__ W_cites, const float* __restrict__ W_writes,
                       const float* __restrict__ Wc_a, const float* __restrict__ Ws_a,
                       const float* __restrict__ W_written,
                       unsigned short* __restrict__ WcatP, unsigned short* __restrict__ WcatA) {
    int m = blockIdx.x >> 7;
    int r = blockIdx.x & 127;   // output col of GEMM
    int c = threadIdx.x;        // k within 128-segment
    const float* L; const float* R; float scale = 1.f;
    switch (m) {
        case 0:  L = Wc_p + r*256;       R = Ws_p;      break;
        case 1:  L = Wc_p + r*256 + 128; R = W_cites;   scale = 0.5f; break;
        case 2:  L = Wc_p + r*256 + 128; R = W_writes;  scale = 0.5f; break;
        case 3:  L = Wc_a + r*256;       R = Ws_a;      break;
        default: L = Wc_a + r*256 + 128; R = W_written; break;
    }
    float acc = 0.f;
    for (int k = 0; k < 128; ++k) acc += L[k] * R[k*128 + c];
    unsigned short v = f2bf(scale * acc);
    int kcat = (m < 3 ? m : m - 3) * 128 + c;
    int s  = kcat >> 5;
    int kg = (kcat >> 3) & 3;
    int j  = kcat & 7;
    int cg = r >> 4;
    int l15 = r & 15;
    long long idx = ((((long long)s*8 + cg)*64) + kg*16 + l15)*8 + j;
    if (m < 3) WcatP[idx] = v;
    else       WcatA[idx] = v;
}

__global__ void fuse_b(const float* __restrict__ Wc_p, const float* __restrict__ bs_p,
                       const float* __restrict__ bc_p, const float* __restrict__ b_cites,
                       const float* __restrict__ b_writes,
                       const float* __restrict__ Wc_a, const float* __restrict__ bs_a,
                       const float* __restrict__ bc_a, const float* __restrict__ b_written,
                       float* __restrict__ wsB) {
    int t = blockIdx.x * blockDim.x + threadIdx.x;
    if (t >= 640) return;
    int m = t >> 7, j = t & 127;
    float acc = 0.f;
    switch (m) {
        case 0:  for (int k = 0; k < 128; ++k) acc += Wc_p[j*256+k]     * bs_p[k];     acc += bc_p[j]; break;
        case 1:  for (int k = 0; k < 128; ++k) acc += Wc_p[j*256+128+k] * b_cites[k];  acc *= 0.5f;    break;
        case 2:  for (int k = 0; k < 128; ++k) acc += Wc_p[j*256+128+k] * b_writes[k]; acc *= 0.5f;    break;
        case 3:  for (int k = 0; k < 128; ++k) acc += Wc_a[j*256+k]     * bs_a[k];     acc += bc_a[j]; break;
        default: for (int k = 0; k < 128; ++k) acc += Wc_a[j*256+128+k] * b_written[k];                break;
    }
    wsB[m*128 + j] = acc;
}

// ---------------- P1: per-(chunk,bin) counts via LDS histogram ----------------
__global__ __launch_bounds__(1024) void part_count(const int* __restrict__ eic,
                                                   const int* __restrict__ eiw,
                                                   const int* __restrict__ eiwr,
                                                   unsigned int* __restrict__ pcnt) {
    __shared__ int lc[512];
    int t = threadIdx.x;
    if (t < 512) lc[t] = 0;
    __syncthreads();
    int base = blockIdx.x * CHUNK;
#pragma unroll
    for (int k = 0; k < 4; ++k) {
        int e = base + k*1024 + t;
        if (e < NE3) atomicAdd(&lc[edst(e, eic, eiw, eiwr) >> BSH], 1);
    }
    __syncthreads();
    if (t < 512) pcnt[blockIdx.x*512 + t] = (unsigned int)lc[t];
}

// ---------------- P2a: bin totals + exclusive scan -> binStart ----------------
__global__ __launch_bounds__(512) void bin_scan(const unsigned int* __restrict__ pcnt,
                                                unsigned int* __restrict__ binStart) {
    __shared__ unsigned int s[512];
    int t = threadIdx.x;
    unsigned int tot = 0;
    for (int c = 0; c < NCHK; ++c) tot += pcnt[c*512 + t];
    s[t] = tot; __syncthreads();
    for (int off = 1; off < 512; off <<= 1) {
        unsigned int u = (t >= off) ? s[t-off] : 0;
        __syncthreads();
        s[t] += u;
        __syncthreads();
    }
    binStart[t] = s[t] - tot;
    if (t == 511) binStart[512] = s[t];   // == NE3
}

// ---------------- P2b: per-bin scan over chunks (in-place pcnt -> offsets) ----
__global__ __launch_bounds__(512) void chunk_scan(unsigned int* __restrict__ pcnt,
                                                  const unsigned int* __restrict__ binStart) {
    __shared__ unsigned int s[512];
    int bin = blockIdx.x;
    int t = threadIdx.x;
    unsigned int v = (t < NCHK) ? pcnt[t*512 + bin] : 0;
    s[t] = v; __syncthreads();
    for (int off = 1; off < 512; off <<= 1) {
        unsigned int u = (t >= off) ? s[t-off] : 0;
        __syncthreads();
        s[t] += u;
        __syncthreads();
    }
    if (t < NCHK) pcnt[t*512 + bin] = binStart[bin] + s[t] - v;
}

// ---------------- P3: partition-scatter, LDS-staged by bin ----------------
__global__ __launch_bounds__(1024) void part_scatter(const int* __restrict__ eic,
                                                     const int* __restrict__ eiw,
                                                     const int* __restrict__ eiwr,
                                                     const unsigned int* __restrict__ pcnt,
                                                     unsigned long long* __restrict__ part) {
    __shared__ unsigned int lcnt[512], lexc[512], lrank[512], ssc[512];
    __shared__ unsigned long long stage[CHUNK];
    int t = threadIdx.x;
    if (t < 512) { lcnt[t] = 0; lrank[t] = 0; }
    __syncthreads();
    int base = blockIdx.x * CHUNK;
    int dd[4], ss4[4];
#pragma unroll
    for (int k = 0; k < 4; ++k) {
        int e = base + k*1024 + t;
        dd[k] = -1;
        if (e < NE3) {
            dd[k] = edst(e, eic, eiw, eiwr);
            ss4[k] = esrc(e, eic, eiw, eiwr);
            atomicAdd(&lcnt[dd[k] >> BSH], 1);
        }
    }
    __syncthreads();
    unsigned int v0 = (t < 512) ? lcnt[t] : 0;
    if (t < 512) ssc[t] = v0;
    __syncthreads();
    for (int off = 1; off < 512; off <<= 1) {
        unsigned int u = 0;
        if (t < 512 && t >= off) u = ssc[t-off];
        __syncthreads();
        if (t < 512) ssc[t] += u;
        __syncthreads();
    }
    if (t < 512) lexc[t] = ssc[t] - v0;
    __syncthreads();
#pragma unroll
    for (int k = 0; k < 4; ++k) {
        if (dd[k] >= 0) {
            int b = dd[k] >> BSH;
            unsigned int r = atomicAdd(&lrank[b], 1);
            stage[lexc[b] + r] = ((unsigned long long)(unsigned int)dd[k] << 32)
                               | (unsigned int)ss4[k];
        }
    }
    __syncthreads();
    int nE = min(NE3 - base, CHUNK);
    for (int i = t; i < nE; i += 1024) {
        unsigned long long pr = stage[i];
        int b = (int)(pr >> 32) >> BSH;
        unsigned int pos = pcnt[blockIdx.x*512 + b] + ((unsigned int)i - lexc[b]);
        part[pos] = pr;
    }
}

// ---------------- P4: bin-local CSR build entirely in LDS ----------------
__global__ __launch_bounds__(1024) void bin_csr(const unsigned long long* __restrict__ part,
                                                const unsigned int* __restrict__ binStart,
                                                int* __restrict__ srcIdx,
                                                int* __restrict__ rowStart,
                                                int* __restrict__ cnt) {
    __shared__ int lcnt[512];
    __shared__ unsigned int lexc[512], ssc[512];
    __shared__ int lsrc[MAXBIN];
    int bin = blockIdx.x, t = threadIdx.x;
    unsigned int beg = binStart[bin];
    int nE = (int)(binStart[bin+1] - beg);
    if (nE > MAXBIN) nE = MAXBIN;
    int d0 = bin << BSH;
    if (t < 512) lcnt[t] = 0;
    __syncthreads();
    for (int i = t; i < nE; i += 1024)
        atomicAdd(&lcnt[(int)(part[beg+i] >> 32) - d0], 1);
    __syncthreads();
    unsigned int v0 = (t < 512) ? (unsigned int)lcnt[t] : 0;
    if (t < 512) ssc[t] = v0;
    __syncthreads();
    for (int off = 1; off < 512; off <<= 1) {
        unsigned int u = 0;
        if (t < 512 && t >= off) u = ssc[t-off];
        __syncthreads();
        if (t < 512) ssc[t] += u;
        __syncthreads();
    }
    if (t < 512) { lexc[t] = ssc[t] - v0; lcnt[t] = 0; }
    __syncthreads();
    for (int i = t; i < nE; i += 1024) {
        unsigned long long pr = part[beg+i];
        int ld = (int)(pr >> 32) - d0;
        int r = atomicAdd(&lcnt[ld], 1);
        lsrc[lexc[ld] + r] = (int)(unsigned int)pr;
    }
    __syncthreads();
    for (int i = t; i < nE; i += 1024) srcIdx[beg + i] = lsrc[i];
    int gd = d0 + t;
    if (t < 512 && gd < NTOT) {
        rowStart[gd] = (int)(beg + lexc[t]);
        cnt[gd] = lcnt[t];
    }
}

// ---------------- merged gather-aggregate: one wave per dst (bf16) -------------
__global__ __launch_bounds__(256) void csr_aggregate3(
        const unsigned int* __restrict__ xbfp,   // ws, row stride 64 u32
        unsigned int* __restrict__ outp_u,       // out_p as u32, row stride 128
        unsigned int* __restrict__ outa_u,       // out_a as u32, row stride 128
        const int* __restrict__ srcIdx, const int* __restrict__ rowStart,
        const int* __restrict__ cnt) {
    int gw = (int)((blockIdx.x * 256 + threadIdx.x) >> 6);
    int lane = threadIdx.x & 63;
    if (gw >= NTOT) return;
    int beg = __builtin_amdgcn_readfirstlane(rowStart[gw]);
    int n   = __builtin_amdgcn_readfirstlane(cnt[gw]);

    const unsigned int* src; int sshift; unsigned int* mean;
    if (gw < NP) {
        src = xbfp; sshift = 6;
        mean = outp_u + (long long)gw * 128 + lane;
    } else if (gw < 2*NP) {
        src = outa_u; sshift = 7;
        mean = outp_u + (long long)(gw - NP) * 128 + 64 + lane;
    } else {
        src = xbfp; sshift = 6;
        mean = outa_u + (long long)(gw - 2*NP) * 128 + 64 + lane;
    }

    float l0=0.f,h0=0.f,l1=0.f,h1=0.f,l2=0.f,h2=0.f,l3=0.f,h3=0.f;
    int nm1 = n - 1;
    for (int j = 0; j < n; j += 8) {
        int s0 = __builtin_amdgcn_readfirstlane(srcIdx[beg + min(j + 0, nm1)]);
        int s1 = __builtin_amdgcn_readfirstlane(srcIdx[beg + min(j + 1, nm1)]);
        int s2 = __builtin_amdgcn_readfirstlane(srcIdx[beg + min(j + 2, nm1)]);
        int s3 = __builtin_amdgcn_readfirstlane(srcIdx[beg + min(j + 3, nm1)]);
        int s4 = __builtin_amdgcn_readfirstlane(srcIdx[beg + min(j + 4, nm1)]);
        int s5 = __builtin_amdgcn_readfirstlane(srcIdx[beg + min(j + 5, nm1)]);
        int s6 = __builtin_amdgcn_readfirstlane(srcIdx[beg + min(j + 6, nm1)]);
        int s7 = __builtin_amdgcn_readfirstlane(srcIdx[beg + min(j + 7, nm1)]);
        unsigned int u0 = src[(s0 << sshift) + lane];
        unsigned int u1 = src[(s1 << sshift) + lane];
        unsigned int u2 = src[(s2 << sshift) + lane];
        unsigned int u3 = src[(s3 << sshift) + lane];
        unsigned int u4 = src[(s4 << sshift) + lane];
        unsigned int u5 = src[(s5 << sshift) + lane];
        unsigned int u6 = src[(s6 << sshift) + lane];
        unsigned int u7 = src[(s7 << sshift) + lane];
        float m1f = (j + 1 < n) ? 1.f : 0.f;
        float m2f = (j + 2 < n) ? 1.f : 0.f;
        float m3f = (j + 3 < n) ? 1.f : 0.f;
        float m4f = (j + 4 < n) ? 1.f : 0.f;
        float m5f = (j + 5 < n) ? 1.f : 0.f;
        float m6f = (j + 6 < n) ? 1.f : 0.f;
        float m7f = (j + 7 < n) ? 1.f : 0.f;
        l0 += bflo(u0);               h0 += bfhi(u0);
        l1 = fmaf(m1f, bflo(u1), l1); h1 = fmaf(m1f, bfhi(u1), h1);
        l2 = fmaf(m2f, bflo(u2), l2); h2 = fmaf(m2f, bfhi(u2), h2);
        l3 = fmaf(m3f, bflo(u3), l3); h3 = fmaf(m3f, bfhi(u3), h3);
        l0 = fmaf(m4f, bflo(u4), l0); h0 = fmaf(m4f, bfhi(u4), h0);
        l1 = fmaf(m5f, bflo(u5), l1); h1 = fmaf(m5f, bfhi(u5), h1);
        l2 = fmaf(m6f, bflo(u6), l2); h2 = fmaf(m6f, bfhi(u6), h2);
        l3 = fmaf(m7f, bflo(u7), l3); h3 = fmaf(m7f, bfhi(u7), h3);
    }
    float lsum = (l0 + l1) + (l2 + l3);
    float hsum = (h0 + h1) + (h2 + h3);
    float sc = 1.f / (float)max(n, 1);
    *mean = pack2(lsum * sc, hsum * sc);
}

// ---------------- MFMA GEMM (frag-major coalesced B loads) ----------------
template<int NSEG, bool S0SAFE, int S0STRIDE>
__global__ __launch_bounds__(256) void mfma_gemm(
        const unsigned short* __restrict__ a0src,
        const unsigned short* __restrict__ m1,    // row stride 256 u16
        const unsigned short* __restrict__ m2,    // row stride 256 u16
        const int* __restrict__ cnt1,
        const int* __restrict__ cnt2,
        const unsigned short* __restrict__ WcatF, // fragment-major
        const float* __restrict__ b0,
        const float* __restrict__ b1,
        const float* __restrict__ b2,
        float* __restrict__ out, int nRows) {
    constexpr int SOFF = S0SAFE ? 4 : 0;
    constexpr int NPRE = NSEG * 4 - SOFF;
    int tid = threadIdx.x;
    int lane = tid & 63;
    int wid = tid >> 6;
    int wm = wid >> 1, wn = wid & 1;
    int row0 = blockIdx.x * 64 + wm * 32;
    int colBase = wn * 64;
    int l15 = lane & 15;
    int kg = lane >> 4;

    int rA0 = min(row0 + l15,      nRows - 1);
    int rA1 = min(row0 + 16 + l15, nRows - 1);

    short8 pa[NPRE][2];
#pragma unroll
    for (int i = 0; i < NPRE; ++i) {
        int s = i + SOFF;
        int kk = (s & 3) * 32 + kg * 8;
        const unsigned short* src = (!S0SAFE && s < 4) ? a0src : ((s >= 8) ? m2 : m1);
        pa[i][0] = *(const short8*)(src + (long long)rA0 * 256 + kk);
        pa[i][1] = *(const short8*)(src + (long long)rA1 * 256 + kk);
    }
    asm volatile("s_waitcnt vmcnt(0)" ::: "memory");  // preloads resident pre-barrier
    __syncthreads();   // all out-buffer reads done before any epilogue write

    floatx4 acc[2][4] = {};

#pragma unroll
    for (int s = 0; s < NSEG * 4; ++s) {
        int kk = (s & 3) * 32 + kg * 8;
        short8 a0, a1;
        if (S0SAFE && s < 4) {
            a0 = *(const short8*)(a0src + (long long)rA0 * S0STRIDE + kk);
            a1 = *(const short8*)(a0src + (long long)rA1 * S0STRIDE + kk);
        } else {
            a0 = pa[s - SOFF][0];
            a1 = pa[s - SOFF][1];
        }
        const unsigned short* wb = WcatF + ((long long)(s*8 + wn*4) * 64 + lane) * 8;
        short8 bf0 = *(const short8*)(wb);
        short8 bf1 = *(const short8*)(wb + 64*8);
        short8 bf2 = *(const short8*)(wb + 2*64*8);
        short8 bf3 = *(const short8*)(wb + 3*64*8);

        acc[0][0] = __builtin_amdgcn_mfma_f32_16x16x32_bf16(a0, bf0, acc[0][0], 0, 0, 0);
        acc[0][1] = __builtin_amdgcn_mfma_f32_16x16x32_bf16(a0, bf1, acc[0][1], 0, 0, 0);
        acc[0][2] = __builtin_amdgcn_mfma_f32_16x16x32_bf16(a0, bf2, acc[0][2], 0, 0, 0);
        acc[0][3] = __builtin_amdgcn_mfma_f32_16x16x32_bf16(a0, bf3, acc[0][3], 0, 0, 0);
        acc[1][0] = __builtin_amdgcn_mfma_f32_16x16x32_bf16(a1, bf0, acc[1][0], 0, 0, 0);
        acc[1][1] = __builtin_amdgcn_mfma_f32_16x16x32_bf16(a1, bf1, acc[1][1], 0, 0, 0);
        acc[1][2] = __builtin_amdgcn_mfma_f32_16x16x32_bf16(a1, bf2, acc[1][2], 0, 0, 0);
        acc[1][3] = __builtin_amdgcn_mfma_f32_16x16x32_bf16(a1, bf3, acc[1][3], 0, 0, 0);
    }

    float bb0[4], bb1[4], bb2[4];
#pragma unroll
    for (int n = 0; n < 4; ++n) {
        int col = colBase + n * 16 + l15;
        bb0[n] = b0[col];
        bb1[n] = b1[col];
        bb2[n] = (NSEG == 3) ? b2[col] : 0.f;
    }
    int rb = kg * 4;
#pragma unroll
    for (int m = 0; m < 2; ++m) {
#pragma unroll
        for (int r = 0; r < 4; ++r) {
            int gr = row0 + m * 16 + rb + r;
            if (gr >= nRows) continue;
            float mk1 = (cnt1[gr] > 0) ? 1.f : 0.f;
            float mk2 = (NSEG == 3) ? ((cnt2[gr] > 0) ? 1.f : 0.f) : 0.f;
            float* op = out + (long long)gr * 128 + colBase + l15;
#pragma unroll
            for (int n = 0; n < 4; ++n) {
                float v = acc[m][n][r] + bb0[n] + mk1 * bb1[n] + mk2 * bb2[n];
                op[n * 16] = fmaxf(v, 0.f);
            }
        }
    }
}

extern "C" void kernel_launch(void* const* d_in, const int* in_sizes, int n_in,
                              void* d_out, int out_size, void* d_ws, size_t ws_size,
                              hipStream_t stream) {
    const float* x_paper   = (const float*)d_in[0];
    const float* x_author  = (const float*)d_in[1];
    const int*   ei_cites  = (const int*)d_in[2];
    const int*   ei_writes = (const int*)d_in[3];
    const int*   ei_written= (const int*)d_in[4];
    const float* W_cites   = (const float*)d_in[5];
    const float* b_cites   = (const float*)d_in[6];
    const float* W_writes  = (const float*)d_in[7];
    const float* b_writes  = (const float*)d_in[8];
    const float* W_written = (const float*)d_in[9];
    const float* b_written = (const float*)d_in[10];
    const float* Ws_paper  = (const float*)d_in[11];
    const float* bs_paper  = (const float*)d_in[12];
    const float* Ws_author = (const float*)d_in[13];
    const float* bs_author = (const float*)d_in[14];
    const float* Wc_paper  = (const float*)d_in[15];
    const float* bc_paper  = (const float*)d_in[16];
    const float* Wc_author = (const float*)d_in[17];
    const float* bc_author = (const float*)d_in[18];

    char* ws = (char*)d_ws;
    unsigned int* xbf_p = (unsigned int*)ws;
    int* cnt      = (int*)(ws + OFF_CNT);
    int* rowStart = (int*)(ws + OFF_ROW);
    int* srcIdx   = (int*)(ws + OFF_SRC);
    unsigned long long* part = (unsigned long long*)(ws + OFF_PART);
    unsigned int* pcnt     = (unsigned int*)(ws + OFF_PCNT);
    unsigned int* binStart = (unsigned int*)(ws + OFF_BST);
    unsigned short* WcatP = (unsigned short*)(ws + OFF_WP);
    unsigned short* WcatA = (unsigned short*)(ws + OFF_WA);
    float* wsB = (float*)(ws + OFF_B);
    const float* bp0 = wsB;
    const float* bpc = wsB + 128;
    const float* bpw = wsB + 2*128;
    const float* ba0 = wsB + 3*128;
    const float* bab = wsB + 4*128;

    float* out_p = (float*)d_out;
    float* out_a = out_p + (long long)NP*HID;
    unsigned int* outp_u = (unsigned int*)out_p;
    unsigned int* outa_u = (unsigned int*)out_a;

    // bf16 stashes: x_paper -> ws; x_author -> out_a low halves
    to_bf16_both<<<((NP+NA)*16 + 255) / 256, 256, 0, stream>>>(
        x_paper, x_author, xbf_p, outa_u);
    fuse_w<<<640, 128, 0, stream>>>(Wc_paper, Ws_paper, W_cites, W_writes,
                                    Wc_author, Ws_author, W_written, WcatP, WcatA);
    fuse_b<<<3, 256, 0, stream>>>(Wc_paper, bs_paper, bc_paper, b_cites, b_writes,
                                  Wc_author, bs_author, bc_author, b_written, wsB);

    // CSR build via two-level LDS-staged counting sort (zero global scatter)
    part_count  <<<NCHK, 1024, 0, stream>>>(ei_cites, ei_writes, ei_written, pcnt);
    bin_scan    <<<1,    512,  0, stream>>>(pcnt, binStart);
    chunk_scan  <<<NBIN, 512,  0, stream>>>(pcnt, binStart);
    part_scatter<<<NCHK, 1024, 0, stream>>>(ei_cites, ei_writes, ei_written, pcnt, part);
    bin_csr     <<<NBIN, 1024, 0, stream>>>(part, binStart, srcIdx, rowStart, cnt);

    // merged aggregate: writes means interleaved into d_out
    csr_aggregate3<<<(NTOT * 64) / 256, 256, 0, stream>>>(
        xbf_p, outp_u, outa_u, srcIdx, rowStart, cnt);

    // paper GEMM: seg0 = xbf_p (ws); m1/m2 = out_p interleaved
    mfma_gemm<3, true, 128><<<(NP + 63) / 64, 256, 0, stream>>>(
        (const unsigned short*)xbf_p,
        (const unsigned short*)outp_u, (const unsigned short*)outp_u + 128,
        cnt, cnt + NP, WcatP, bp0, bpc, bpw, out_p, NP);

    // author GEMM: seg0 = xbf_a (out_a low), m1 = ma (out_a high)
    mfma_gemm<2, false, 256><<<(NA + 63) / 64, 256, 0, stream>>>(
        (const unsigned short*)outa_u,
        (const unsigned short*)outa_u + 128, nullptr,
        cnt + 2*NP, nullptr, WcatA, ba0, bab, nullptr, out_a, NA);
}